// Round 1
// baseline (6850.484 us; speedup 1.0000x reference)
//
#include <hip/hip_runtime.h>
#include <math.h>

#define BN_EPS 1e-5f

// Transposed weight layouts: [ci][co][t] (t fastest, co next) so a wave's
// 16/8/4-channel slice for one ci is contiguous -> uniform float4 loads.
__device__ __align__(16) float g_wgT[24576];   // gating conv1: [128][64][3]
__device__ __align__(16) float g_we1T[73728];  // expert conv1: [3][128][64][3]
__device__ __align__(16) float g_we2T[18432];  // expert conv2: [3][64][32][3]
__device__ __align__(16) float g_we3T[4608];   // expert conv3: [3][32][16][3]

__global__ __launch_bounds__(256) void transpose_w_kernel(
    const float* __restrict__ gw, const float* __restrict__ e1w,
    const float* __restrict__ e2w, const float* __restrict__ e3w) {
  int idx = blockIdx.x * 256 + threadIdx.x;
  if (idx < 24576) {
    int t = idx % 3, r = idx / 3;
    int co = r & 63, ci = r >> 6;
    g_wgT[idx] = gw[(co * 128 + ci) * 3 + t];
  } else if (idx < 24576 + 73728) {
    int j = idx - 24576;
    int e = j / 24576, jj = j % 24576;
    int t = jj % 3, r = jj / 3;
    int co = r & 63, ci = r >> 6;
    g_we1T[j] = e1w[e * 24576 + (co * 128 + ci) * 3 + t];
  } else if (idx < 24576 + 73728 + 18432) {
    int j = idx - (24576 + 73728);
    int e = j / 6144, jj = j % 6144;
    int t = jj % 3, r = jj / 3;
    int co = r & 31, ci = r >> 5;
    g_we2T[j] = e2w[e * 6144 + (co * 64 + ci) * 3 + t];
  } else if (idx < 24576 + 73728 + 18432 + 4608) {
    int j = idx - (24576 + 73728 + 18432);
    int e = j / 1536, jj = j % 1536;
    int t = jj % 3, r = jj / 3;
    int co = r & 15, ci = r >> 4;
    g_we3T[j] = e3w[e * 1536 + (co * 32 + ci) * 3 + t];
  }
}

// conv with k=3 over padded-LDS input rows. wT row stride = COTOT*3.
// Each lane is one L-position; accumulates NCO output channels.
template <int CIN, int COTOT, int NCO>
__device__ __forceinline__ void conv3x(const float* __restrict__ wT,
                                       const float (*E)[63], int l, int coB,
                                       float* acc) {
#pragma unroll 2
  for (int ci = 0; ci < CIN; ++ci) {
    float e0 = E[ci][l];
    float e1 = E[ci][l + 1];
    float e2 = E[ci][l + 2];
    const float4* wp =
        reinterpret_cast<const float4*>(wT + ci * (COTOT * 3) + coB * 3);
    float w[NCO * 3];
#pragma unroll
    for (int q = 0; q < (NCO * 3) / 4; ++q) {
      float4 v = wp[q];
      w[4 * q + 0] = v.x;
      w[4 * q + 1] = v.y;
      w[4 * q + 2] = v.z;
      w[4 * q + 3] = v.w;
    }
#pragma unroll
    for (int k = 0; k < NCO; ++k) {
      acc[k] = fmaf(e0, w[3 * k + 0],
                    fmaf(e1, w[3 * k + 1], fmaf(e2, w[3 * k + 2], acc[k])));
    }
  }
}

__global__ __launch_bounds__(256) void moe_fused_kernel(
    const int* __restrict__ x, const float* __restrict__ embt,
    const float* __restrict__ gcb, const float* __restrict__ gbn,
    const float* __restrict__ gf1w, const float* __restrict__ gf1b,
    const float* __restrict__ gf2w, const float* __restrict__ gf2b,
    const float* __restrict__ e1b, const float* __restrict__ ebn1,
    const float* __restrict__ e2b, const float* __restrict__ ebn2,
    const float* __restrict__ e3b, const float* __restrict__ ebn3,
    const float* __restrict__ f1w, const float* __restrict__ f1b,
    const float* __restrict__ f2w, const float* __restrict__ f2b,
    float* __restrict__ out) {
  __shared__ float Ebuf[128][63];  // emb (padded cols 0 & 61); later reused for conv2 out
  __shared__ float Bbuf[64][63];   // expert conv1 out
  __shared__ float hbuf[64];
  __shared__ float h2buf[32];
  __shared__ float glog[3];
  __shared__ int selbuf;
  __shared__ int toks[60];
  __shared__ float mbuf[16];
  __shared__ float o64[64];

  const int b = blockIdx.x;
  const int tid = threadIdx.x;
  const int lane = tid & 63;
  const int wv = tid >> 6;

  if (tid < 60) toks[tid] = x[b * 60 + tid];
  if (tid < 128) {
    Ebuf[tid][0] = 0.f;
    Ebuf[tid][61] = 0.f;
  }
  __syncthreads();
  // gather: idx = l*128 + d -> coalesced emb_table row reads
  for (int idx = tid; idx < 128 * 60; idx += 256) {
    int l = idx >> 7, d = idx & 127;
    Ebuf[d][l + 1] = embt[toks[l] * 128 + d];
  }
  __syncthreads();

  // ---- gating conv1 + BN + ReLU + max over L ----
  {
    float acc[16] = {};
    const int coB = wv * 16;
    if (lane < 60) conv3x<128, 64, 16>(g_wgT, Ebuf, lane, coB, acc);
#pragma unroll
    for (int k = 0; k < 16; ++k) {
      int co = coB + k;
      float inv = gbn[co] / sqrtf(gbn[192 + co] + BN_EPS);
      float add = gbn[64 + co] + (gcb[co] - gbn[128 + co]) * inv;
      float v = (lane < 60) ? fmaxf(fmaf(acc[k], inv, add), 0.f) : -1e30f;
      for (int off = 32; off; off >>= 1) v = fmaxf(v, __shfl_xor(v, off, 64));
      if (lane == 0) hbuf[co] = v;
    }
  }
  __syncthreads();

  // ---- gating MLP 64->32->3, argmax ----
  if (tid < 32) {
    float a = gf1b[tid];
#pragma unroll 8
    for (int k = 0; k < 64; ++k) a = fmaf(hbuf[k], gf1w[tid * 64 + k], a);
    h2buf[tid] = fmaxf(a, 0.f);
  }
  __syncthreads();
  if (tid < 3) {
    float a = gf2b[tid];
#pragma unroll 8
    for (int k = 0; k < 32; ++k) a = fmaf(h2buf[k], gf2w[tid * 32 + k], a);
    glog[tid] = a;
  }
  __syncthreads();
  if (tid == 0) {
    int best = 0;
    float bv = glog[0];
    if (glog[1] > bv) { bv = glog[1]; best = 1; }
    if (glog[2] > bv) { best = 2; }
    selbuf = best;
  }
  __syncthreads();
  const int e = selbuf;

  // ---- expert conv1 -> Bbuf (BN+ReLU) ----
  {
    float acc[16] = {};
    const int coB = wv * 16;
    if (lane < 60) conv3x<128, 64, 16>(g_we1T + e * 24576, Ebuf, lane, coB, acc);
    const float* bn1 = ebn1 + e * 256;
    const float* cb1 = e1b + e * 64;
#pragma unroll
    for (int k = 0; k < 16; ++k) {
      int co = coB + k;
      float inv = bn1[co] / sqrtf(bn1[192 + co] + BN_EPS);
      float add = bn1[64 + co] + (cb1[co] - bn1[128 + co]) * inv;
      if (lane < 60) Bbuf[co][lane + 1] = fmaxf(fmaf(acc[k], inv, add), 0.f);
    }
  }
  if (tid < 64) {
    Bbuf[tid][0] = 0.f;
    Bbuf[tid][61] = 0.f;
  }
  __syncthreads();

  // ---- expert conv2: Bbuf -> C2 (overlays dead Ebuf) ----
  float(*C2)[63] = (float(*)[63])Ebuf;
  {
    float acc[8] = {};
    const int coB = wv * 8;
    if (lane < 60) conv3x<64, 32, 8>(g_we2T + e * 6144, Bbuf, lane, coB, acc);
    const float* bn2 = ebn2 + e * 128;
    const float* cb2 = e2b + e * 32;
#pragma unroll
    for (int k = 0; k < 8; ++k) {
      int co = coB + k;
      float inv = bn2[co] / sqrtf(bn2[96 + co] + BN_EPS);
      float add = bn2[32 + co] + (cb2[co] - bn2[64 + co]) * inv;
      if (lane < 60) C2[co][lane + 1] = fmaxf(fmaf(acc[k], inv, add), 0.f);
    }
  }
  if (tid < 32) {
    C2[tid][0] = 0.f;
    C2[tid][61] = 0.f;
  }
  __syncthreads();

  // ---- expert conv3 + BN + ReLU + max over L -> mbuf[16] ----
  {
    float acc[4] = {};
    const int coB = wv * 4;
    if (lane < 60) conv3x<32, 16, 4>(g_we3T + e * 1536, C2, lane, coB, acc);
    const float* bn3 = ebn3 + e * 64;
    const float* cb3 = e3b + e * 16;
#pragma unroll
    for (int k = 0; k < 4; ++k) {
      int co = coB + k;
      float inv = bn3[co] / sqrtf(bn3[48 + co] + BN_EPS);
      float add = bn3[16 + co] + (cb3[co] - bn3[32 + co]) * inv;
      float v = (lane < 60) ? fmaxf(fmaf(acc[k], inv, add), 0.f) : -1e30f;
      for (int off = 32; off; off >>= 1) v = fmaxf(v, __shfl_xor(v, off, 64));
      if (lane == 0) mbuf[co] = v;
    }
  }
  __syncthreads();

  // ---- head MLP 16->64->2 ----
  if (tid < 64) {
    float a = f1b[tid];
#pragma unroll
    for (int k = 0; k < 16; ++k) a = fmaf(mbuf[k], f1w[tid * 16 + k], a);
    o64[tid] = fmaxf(a, 0.f);
  }
  __syncthreads();
  if (tid < 2) {
    float a = f2b[tid];
#pragma unroll 8
    for (int k = 0; k < 64; ++k) a = fmaf(o64[k], f2w[tid * 64 + k], a);
    out[b * 2 + tid] = a;
  }
}

extern "C" void kernel_launch(void* const* d_in, const int* in_sizes, int n_in,
                              void* d_out, int out_size, void* d_ws,
                              size_t ws_size, hipStream_t stream) {
  const int* x = (const int*)d_in[0];
  const float* embt = (const float*)d_in[1];
  const float* gcw = (const float*)d_in[2];
  const float* gcb = (const float*)d_in[3];
  const float* gbn = (const float*)d_in[4];
  const float* gf1w = (const float*)d_in[5];
  const float* gf1b = (const float*)d_in[6];
  const float* gf2w = (const float*)d_in[7];
  const float* gf2b = (const float*)d_in[8];
  const float* e1w = (const float*)d_in[9];
  const float* e1b = (const float*)d_in[10];
  const float* ebn1 = (const float*)d_in[11];
  const float* e2w = (const float*)d_in[12];
  const float* e2b = (const float*)d_in[13];
  const float* ebn2 = (const float*)d_in[14];
  const float* e3w = (const float*)d_in[15];
  const float* e3b = (const float*)d_in[16];
  const float* ebn3 = (const float*)d_in[17];
  const float* f1w = (const float*)d_in[18];
  const float* f1b = (const float*)d_in[19];
  const float* f2w = (const float*)d_in[20];
  const float* f2b = (const float*)d_in[21];
  float* out = (float*)d_out;

  const int B = in_sizes[0] / 60;  // 16384

  transpose_w_kernel<<<(121344 + 255) / 256, 256, 0, stream>>>(gcw, e1w, e2w,
                                                               e3w);
  moe_fused_kernel<<<B, 256, 0, stream>>>(
      x, embt, gcb, gbn, gf1w, gf1b, gf2w, gf2b, e1b, ebn1, e2b, ebn2, e3b,
      ebn3, f1w, f1b, f2w, f2b, out);
}

// Round 2
// 1997.893 us; speedup vs baseline: 3.4289x; 3.4289x over previous
//
#include <hip/hip_runtime.h>
#include <math.h>

#define BN_EPS 1e-5f
#define STR 65  // odd LDS row stride: conflict-free col-major writes + row reads

// Transposed weight layouts: [ci][co][t] (t fastest, co next) so a lane's
// 4-channel slice for one ci is 12 consecutive floats -> 3 float4 loads.
__device__ __align__(16) float g_wgT[24576];   // gating conv1: [128][64][3]
__device__ __align__(16) float g_we1T[73728];  // expert conv1: [3][128][64][3]
__device__ __align__(16) float g_we2T[18432];  // expert conv2: [3][64][32][3]
__device__ __align__(16) float g_we3T[4608];   // expert conv3: [3][32][16][3]

__global__ __launch_bounds__(256) void transpose_w_kernel(
    const float* __restrict__ gw, const float* __restrict__ e1w,
    const float* __restrict__ e2w, const float* __restrict__ e3w) {
  int idx = blockIdx.x * 256 + threadIdx.x;
  if (idx < 24576) {
    int t = idx % 3, r = idx / 3;
    int co = r & 63, ci = r >> 6;
    g_wgT[idx] = gw[(co * 128 + ci) * 3 + t];
  } else if (idx < 24576 + 73728) {
    int j = idx - 24576;
    int e = j / 24576, jj = j % 24576;
    int t = jj % 3, r = jj / 3;
    int co = r & 63, ci = r >> 6;
    g_we1T[j] = e1w[e * 24576 + (co * 128 + ci) * 3 + t];
  } else if (idx < 24576 + 73728 + 18432) {
    int j = idx - (24576 + 73728);
    int e = j / 6144, jj = j % 6144;
    int t = jj % 3, r = jj / 3;
    int co = r & 31, ci = r >> 5;
    g_we2T[j] = e2w[e * 6144 + (co * 64 + ci) * 3 + t];
  } else if (idx < 24576 + 73728 + 18432 + 4608) {
    int j = idx - (24576 + 73728 + 18432);
    int e = j / 1536, jj = j % 1536;
    int t = jj % 3, r = jj / 3;
    int co = r & 15, ci = r >> 4;
    g_we3T[j] = e3w[e * 1536 + (co * 32 + ci) * 3 + t];
  }
}

// Each lane: 4 output channels (cob..cob+3) x NL output positions.
// Input row layout: col c holds position l = c-1 (col 0 = left zero-pad).
// Output position l needs cols l..l+2; outputs NL*lgrp..NL*lgrp+NL-1 read
// cols col0..col0+NL+1 where col0 = NL*lgrp.
template <int CIN, int CO, int NL>
__device__ __forceinline__ void convNL(const float* __restrict__ wT,
                                       const float* __restrict__ E, int col0,
                                       int cob, float (&acc)[4][NL]) {
#pragma unroll 4
  for (int ci = 0; ci < CIN; ++ci) {
    float e[NL + 2];
    const float* row = E + ci * STR + col0;
#pragma unroll
    for (int j = 0; j < NL + 2; ++j) e[j] = row[j];
    const float4* wp =
        reinterpret_cast<const float4*>(wT + (ci * CO + cob) * 3);
    float4 w0 = wp[0], w1 = wp[1], w2 = wp[2];
    const float w[12] = {w0.x, w0.y, w0.z, w0.w, w1.x, w1.y,
                         w1.z, w1.w, w2.x, w2.y, w2.z, w2.w};
#pragma unroll
    for (int k = 0; k < 4; ++k)
#pragma unroll
      for (int l = 0; l < NL; ++l)
        acc[k][l] = fmaf(e[l], w[3 * k],
                         fmaf(e[l + 1], w[3 * k + 1],
                              fmaf(e[l + 2], w[3 * k + 2], acc[k][l])));
  }
}

__global__ __launch_bounds__(256, 3) void moe_fused_kernel(
    const int* __restrict__ x, const float* __restrict__ embt,
    const float* __restrict__ gcb, const float* __restrict__ gbn,
    const float* __restrict__ gf1w, const float* __restrict__ gf1b,
    const float* __restrict__ gf2w, const float* __restrict__ gf2b,
    const float* __restrict__ e1b, const float* __restrict__ ebn1,
    const float* __restrict__ e2b, const float* __restrict__ ebn2,
    const float* __restrict__ e3b, const float* __restrict__ ebn3,
    const float* __restrict__ f1w, const float* __restrict__ f1b,
    const float* __restrict__ f2w, const float* __restrict__ f2b,
    float* __restrict__ out) {
  // one flat shared block so deliberate small overflow-reads stay in-bounds
  __shared__ float smem[12720];
  float* Ebuf = smem;                   // [128][STR]
  float* Bbuf = smem + 128 * STR;       // [64][STR]
  float* hbuf = smem + 192 * STR;       // 64
  float* h2buf = hbuf + 64;             // 32
  float* glog = h2buf + 32;             // 3
  float* mbuf = glog + 4;               // 16
  float* o64 = mbuf + 16;               // 64
  __shared__ int toks[60];
  __shared__ int selbuf;

  const int b = blockIdx.x;
  const int tid = threadIdx.x;
  const int lane = tid & 63;
  const int wv = tid >> 6;

  if (tid < 60) toks[tid] = x[b * 60 + tid];
  // zero pad columns {0, 61..64} of Ebuf (128 rows) and Bbuf (64 rows)
  for (int i = tid; i < 960; i += 256) {
    int r = i / 5, c = i % 5;
    int col = (c == 0) ? 0 : (60 + c);
    smem[r * STR + col] = 0.f;  // rows 0..127 = Ebuf, 128..191 = Bbuf
  }
  __syncthreads();
  // emb gather: coalesced reads of emb rows; writes (d varies) conflict-free
  // because STR is odd.
  for (int idx = tid; idx < 128 * 60; idx += 256) {
    int l = idx >> 7, d = idx & 127;
    Ebuf[d * STR + (l + 1)] = embt[toks[l] * 128 + d];
  }
  __syncthreads();

  const int lgrp = lane & 15;       // conv1: 16 L-groups of 4
  const int co4 = lane >> 4;        // conv1: 4 channel-groups of 4

  // ---- gating conv1 + BN + ReLU + max over L ----
  {
    float acc[4][4] = {};
    const int cob = wv * 16 + co4 * 4;
    convNL<128, 64, 4>(g_wgT, Ebuf, 4 * lgrp, cob, acc);
    const bool valid = (lgrp < 15);  // lgrp 15 -> l=60..63, discard
#pragma unroll
    for (int k = 0; k < 4; ++k) {
      int co = cob + k;
      float inv = gbn[co] / sqrtf(gbn[192 + co] + BN_EPS);
      float add = gbn[64 + co] + (gcb[co] - gbn[128 + co]) * inv;
      float m = -1e30f;
#pragma unroll
      for (int l = 0; l < 4; ++l)
        m = fmaxf(m, fmaxf(fmaf(acc[k][l], inv, add), 0.f));
      m = valid ? m : -1e30f;
#pragma unroll
      for (int off = 1; off < 16; off <<= 1) m = fmaxf(m, __shfl_xor(m, off, 64));
      if (lgrp == 0) hbuf[co] = m;
    }
  }
  __syncthreads();

  // ---- gating MLP 64->32->3, argmax ----
  if (tid < 32) {
    float a = gf1b[tid];
#pragma unroll 8
    for (int k = 0; k < 64; ++k) a = fmaf(hbuf[k], gf1w[tid * 64 + k], a);
    h2buf[tid] = fmaxf(a, 0.f);
  }
  __syncthreads();
  if (tid < 3) {
    float a = gf2b[tid];
#pragma unroll 8
    for (int k = 0; k < 32; ++k) a = fmaf(h2buf[k], gf2w[tid * 32 + k], a);
    glog[tid] = a;
  }
  __syncthreads();
  if (tid == 0) {
    int best = 0;
    float bv = glog[0];
    if (glog[1] > bv) { bv = glog[1]; best = 1; }
    if (glog[2] > bv) { best = 2; }
    selbuf = best;
  }
  __syncthreads();
  const int e = selbuf;

  // ---- expert conv1 -> Bbuf (BN+ReLU) ----
  {
    float acc[4][4] = {};
    const int cob = wv * 16 + co4 * 4;
    convNL<128, 64, 4>(g_we1T + e * 24576, Ebuf, 4 * lgrp, cob, acc);
    const float* bn1 = ebn1 + e * 256;
    const float* cb1 = e1b + e * 64;
#pragma unroll
    for (int k = 0; k < 4; ++k) {
      int co = cob + k;
      float inv = bn1[co] / sqrtf(bn1[192 + co] + BN_EPS);
      float add = bn1[64 + co] + (cb1[co] - bn1[128 + co]) * inv;
      if (lgrp < 15) {
#pragma unroll
        for (int l = 0; l < 4; ++l)
          Bbuf[co * STR + (4 * lgrp + 1 + l)] =
              fmaxf(fmaf(acc[k][l], inv, add), 0.f);
      }
    }
  }
  __syncthreads();

  // ---- expert conv2: Bbuf -> C2 (overlays dead Ebuf rows 0..31) ----
  float* C2 = Ebuf;
  {
    float acc[4][2] = {};
    const int lg2 = lane & 31, cg2 = lane >> 5;  // 32 L-groups of 2, 2 ch-groups
    const int cob = wv * 8 + cg2 * 4;
    convNL<64, 32, 2>(g_we2T + e * 6144, Bbuf, 2 * lg2, cob, acc);
    const float* bn2 = ebn2 + e * 128;
    const float* cb2 = e2b + e * 32;
#pragma unroll
    for (int k = 0; k < 4; ++k) {
      int co = cob + k;
      float inv = bn2[co] / sqrtf(bn2[96 + co] + BN_EPS);
      float add = bn2[32 + co] + (cb2[co] - bn2[64 + co]) * inv;
      if (lg2 < 30) {
#pragma unroll
        for (int l = 0; l < 2; ++l)
          C2[co * STR + (2 * lg2 + 1 + l)] =
              fmaxf(fmaf(acc[k][l], inv, add), 0.f);
      }
    }
  }
  __syncthreads();

  // ---- expert conv3 + BN + ReLU + max over L -> mbuf[16] ----
  {
    float acc[4][1] = {};
    const int cob = wv * 4;  // each lane = one L position, 4 channels
    convNL<32, 16, 1>(g_we3T + e * 1536, C2, lane, cob, acc);
    const float* bn3 = ebn3 + e * 64;
    const float* cb3 = e3b + e * 16;
    const bool valid = (lane < 60);
#pragma unroll
    for (int k = 0; k < 4; ++k) {
      int co = cob + k;
      float inv = bn3[co] / sqrtf(bn3[48 + co] + BN_EPS);
      float add = bn3[16 + co] + (cb3[co] - bn3[32 + co]) * inv;
      float v = valid ? fmaxf(fmaf(acc[k][0], inv, add), 0.f) : -1e30f;
#pragma unroll
      for (int off = 1; off < 64; off <<= 1) v = fmaxf(v, __shfl_xor(v, off, 64));
      if (lane == 0) mbuf[co] = v;
    }
  }
  __syncthreads();

  // ---- head MLP 16->64->2 ----
  if (tid < 64) {
    float a = f1b[tid];
#pragma unroll
    for (int k = 0; k < 16; ++k) a = fmaf(mbuf[k], f1w[tid * 16 + k], a);
    o64[tid] = fmaxf(a, 0.f);
  }
  __syncthreads();
  if (tid < 2) {
    float a = f2b[tid];
#pragma unroll 8
    for (int k = 0; k < 64; ++k) a = fmaf(o64[k], f2w[tid * 64 + k], a);
    out[b * 2 + tid] = a;
  }
}

extern "C" void kernel_launch(void* const* d_in, const int* in_sizes, int n_in,
                              void* d_out, int out_size, void* d_ws,
                              size_t ws_size, hipStream_t stream) {
  const int* x = (const int*)d_in[0];
  const float* embt = (const float*)d_in[1];
  const float* gcw = (const float*)d_in[2];
  const float* gcb = (const float*)d_in[3];
  const float* gbn = (const float*)d_in[4];
  const float* gf1w = (const float*)d_in[5];
  const float* gf1b = (const float*)d_in[6];
  const float* gf2w = (const float*)d_in[7];
  const float* gf2b = (const float*)d_in[8];
  const float* e1w = (const float*)d_in[9];
  const float* e1b = (const float*)d_in[10];
  const float* ebn1 = (const float*)d_in[11];
  const float* e2w = (const float*)d_in[12];
  const float* e2b = (const float*)d_in[13];
  const float* ebn2 = (const float*)d_in[14];
  const float* e3w = (const float*)d_in[15];
  const float* e3b = (const float*)d_in[16];
  const float* ebn3 = (const float*)d_in[17];
  const float* f1w = (const float*)d_in[18];
  const float* f1b = (const float*)d_in[19];
  const float* f2w = (const float*)d_in[20];
  const float* f2b = (const float*)d_in[21];
  float* out = (float*)d_out;

  const int B = in_sizes[0] / 60;  // 16384

  transpose_w_kernel<<<(121344 + 255) / 256, 256, 0, stream>>>(gcw, e1w, e2w,
                                                               e3w);
  moe_fused_kernel<<<B, 256, 0, stream>>>(
      x, embt, gcb, gbn, gf1w, gf1b, gf2w, gf2b, e1b, ebn1, e2b, ebn2, e3b,
      ebn3, f1w, f1b, f2w, f2b, out);
}

// Round 3
// 1961.067 us; speedup vs baseline: 3.4932x; 1.0188x over previous
//
#include <hip/hip_runtime.h>
#include <math.h>

#define BN_EPS 1e-5f

// Transposed weight layouts: [ci][co][t] (t fastest, co next) so a lane's
// channel slice for one ci is contiguous -> float4/float2 loads.
__device__ __align__(16) float g_wgT[24576];   // gating conv1: [128][64][3]
__device__ __align__(16) float g_we1T[73728];  // expert conv1: [3][128][64][3]
__device__ __align__(16) float g_we2T[18432];  // expert conv2: [3][64][32][3]
__device__ __align__(16) float g_we3T[4608];   // expert conv3: [3][32][16][3]

__global__ __launch_bounds__(256) void transpose_w_kernel(
    const float* __restrict__ gw, const float* __restrict__ e1w,
    const float* __restrict__ e2w, const float* __restrict__ e3w) {
  int idx = blockIdx.x * 256 + threadIdx.x;
  if (idx < 24576) {
    int t = idx % 3, r = idx / 3;
    int co = r & 63, ci = r >> 6;
    g_wgT[idx] = gw[(co * 128 + ci) * 3 + t];
  } else if (idx < 24576 + 73728) {
    int j = idx - 24576;
    int e = j / 24576, jj = j % 24576;
    int t = jj % 3, r = jj / 3;
    int co = r & 63, ci = r >> 6;
    g_we1T[j] = e1w[e * 24576 + (co * 128 + ci) * 3 + t];
  } else if (idx < 24576 + 73728 + 18432) {
    int j = idx - (24576 + 73728);
    int e = j / 6144, jj = j % 6144;
    int t = jj % 3, r = jj / 3;
    int co = r & 31, ci = r >> 5;
    g_we2T[j] = e2w[e * 6144 + (co * 64 + ci) * 3 + t];
  } else if (idx < 24576 + 73728 + 18432 + 4608) {
    int j = idx - (24576 + 73728 + 18432);
    int e = j / 1536, jj = j % 1536;
    int t = jj % 3, r = jj / 3;
    int co = r & 15, ci = r >> 4;
    g_we3T[j] = e3w[e * 1536 + (co * 32 + ci) * 3 + t];
  }
}

// Activation rows are 64 floats (16B-aligned): col c holds position l = c-1
// (col 0 = left zero-pad, cols 61..63 = right zero-pad).
// Each lane: 4 out-channels x 4 positions. e-read = 2 x ds_read_b128 at
// groups {lgrp, lgrp+1}: 16 lanes cover 64 consecutive words -> 2 lanes/bank
// minimum -> conflict-free; 4 co-groups broadcast the same addresses.
template <int CIN, int CO>
__device__ __forceinline__ void conv4x4(const float* __restrict__ wT,
                                        const float* __restrict__ E, int lgrp,
                                        int cob, float (&acc)[4][4]) {
#pragma unroll 4
  for (int ci = 0; ci < CIN; ++ci) {
    const float4* ep = reinterpret_cast<const float4*>(E + ci * 64 + 4 * lgrp);
    float4 ea = ep[0], eb = ep[1];
    const float e[8] = {ea.x, ea.y, ea.z, ea.w, eb.x, eb.y, eb.z, eb.w};
    const float4* wp =
        reinterpret_cast<const float4*>(wT + (ci * CO + cob) * 3);
    float4 w0 = wp[0], w1 = wp[1], w2 = wp[2];
    const float w[12] = {w0.x, w0.y, w0.z, w0.w, w1.x, w1.y,
                         w1.z, w1.w, w2.x, w2.y, w2.z, w2.w};
#pragma unroll
    for (int k = 0; k < 4; ++k)
#pragma unroll
      for (int l = 0; l < 4; ++l)
        acc[k][l] = fmaf(e[l], w[3 * k],
                         fmaf(e[l + 1], w[3 * k + 1],
                              fmaf(e[l + 2], w[3 * k + 2], acc[k][l])));
  }
}

// conv2 variant: 2 out-channels x 4 positions per lane (weights via float2).
template <int CIN, int CO>
__device__ __forceinline__ void conv2x4(const float* __restrict__ wT,
                                        const float* __restrict__ E, int lgrp,
                                        int cob, float (&acc)[2][4]) {
#pragma unroll 4
  for (int ci = 0; ci < CIN; ++ci) {
    const float4* ep = reinterpret_cast<const float4*>(E + ci * 64 + 4 * lgrp);
    float4 ea = ep[0], eb = ep[1];
    const float e[8] = {ea.x, ea.y, ea.z, ea.w, eb.x, eb.y, eb.z, eb.w};
    const float2* wp =
        reinterpret_cast<const float2*>(wT + (ci * CO + cob) * 3);
    float2 w0 = wp[0], w1 = wp[1], w2 = wp[2];
    const float w[6] = {w0.x, w0.y, w1.x, w1.y, w2.x, w2.y};
#pragma unroll
    for (int k = 0; k < 2; ++k)
#pragma unroll
      for (int l = 0; l < 4; ++l)
        acc[k][l] = fmaf(e[l], w[3 * k],
                         fmaf(e[l + 1], w[3 * k + 1],
                              fmaf(e[l + 2], w[3 * k + 2], acc[k][l])));
  }
}

__global__ __launch_bounds__(256, 3) void moe_fused_kernel(
    const int* __restrict__ x, const float* __restrict__ embt,
    const float* __restrict__ gcb, const float* __restrict__ gbn,
    const float* __restrict__ gf1w, const float* __restrict__ gf1b,
    const float* __restrict__ gf2w, const float* __restrict__ gf2b,
    const float* __restrict__ e1b, const float* __restrict__ ebn1,
    const float* __restrict__ e2b, const float* __restrict__ ebn2,
    const float* __restrict__ e3b, const float* __restrict__ ebn3,
    const float* __restrict__ f1w, const float* __restrict__ f1b,
    const float* __restrict__ f2w, const float* __restrict__ f2b,
    float* __restrict__ out) {
  // One flat block: deliberate discarded-edge overreads stay in-bounds.
  // [0,8192)       Ebuf  [128][64]   (later rows 0..31 reused as C2 [32][64])
  // [8192,12288)   Bbuf  [64][64]    (first reused as Tbuf [60][65] staging)
  // [12288,...)    hbuf64 h2buf32 glog4 mbuf16 o64[64]
  __shared__ __align__(16) float smem[12480];
  float* Ebuf = smem;
  float* Bbuf = smem + 8192;
  float* Tbuf = smem + 8192;  // 60*65 = 3900 <= 4096, dead before Bbuf written
  float* hbuf = smem + 12288;
  float* h2buf = hbuf + 64;
  float* glog = h2buf + 32;
  float* mbuf = glog + 4;
  float* o64 = mbuf + 16;
  __shared__ int toks[60];
  __shared__ int selbuf;

  const int b = blockIdx.x;
  const int tid = threadIdx.x;
  const int lane = tid & 63;
  const int wv = tid >> 6;

  if (tid < 60) toks[tid] = x[b * 60 + tid];
  // zero pad cols {0,61,62,63} of Ebuf's 128 rows (512 entries)
  {
    int r = tid >> 1;
    int c = (tid & 1) ? 61 : 0;
    Ebuf[r * 64 + c] = 0.f;
    Ebuf[r * 64 + c + ((tid & 1) ? 1 : 0)] = 0.f;  // 61,62 for odd
    if (tid & 1) Ebuf[r * 64 + 63] = 0.f;
  }
  __syncthreads();

  // ---- emb gather via two-stage transpose (all LDS ops conflict-free) ----
  for (int p = 0; p < 2; ++p) {
    // stage 1: coalesced global read -> Tbuf[l][dp] (stride-1 writes)
    for (int i = tid; i < 60 * 64; i += 256) {
      int l = i >> 6, dp = i & 63;
      Tbuf[l * 65 + dp] = embt[toks[l] * 128 + 64 * p + dp];
    }
    __syncthreads();
    // stage 2: Tbuf (stride-65 reads, conflict-free) -> Ebuf rows (stride-1)
    for (int dp = wv; dp < 64; dp += 4) {
      if (lane < 60) {
        float v = Tbuf[lane * 65 + dp];
        Ebuf[(64 * p + dp) * 64 + lane + 1] = v;
      }
    }
    __syncthreads();
  }

  const int lgrp = lane & 15;  // 16 L-groups of 4 (group 15 discarded)
  const int co4 = lane >> 4;   // 4 channel-groups of 4

  // ---- gating conv1 + BN + ReLU + max over L ----
  {
    float acc[4][4] = {};
    const int cob = wv * 16 + co4 * 4;
    conv4x4<128, 64>(g_wgT, Ebuf, lgrp, cob, acc);
    const bool valid = (lgrp < 15);
#pragma unroll
    for (int k = 0; k < 4; ++k) {
      int co = cob + k;
      float inv = gbn[co] / sqrtf(gbn[192 + co] + BN_EPS);
      float add = gbn[64 + co] + (gcb[co] - gbn[128 + co]) * inv;
      float m = -1e30f;
#pragma unroll
      for (int l = 0; l < 4; ++l)
        m = fmaxf(m, fmaxf(fmaf(acc[k][l], inv, add), 0.f));
      m = valid ? m : -1e30f;
#pragma unroll
      for (int off = 1; off < 16; off <<= 1)
        m = fmaxf(m, __shfl_xor(m, off, 64));
      if (lgrp == 0) hbuf[co] = m;
    }
  }
  __syncthreads();

  // ---- gating MLP 64->32->3, argmax ----
  if (tid < 32) {
    float a = gf1b[tid];
#pragma unroll 8
    for (int k = 0; k < 64; ++k) a = fmaf(hbuf[k], gf1w[tid * 64 + k], a);
    h2buf[tid] = fmaxf(a, 0.f);
  }
  __syncthreads();
  if (tid < 3) {
    float a = gf2b[tid];
#pragma unroll 8
    for (int k = 0; k < 32; ++k) a = fmaf(h2buf[k], gf2w[tid * 32 + k], a);
    glog[tid] = a;
  }
  __syncthreads();
  if (tid == 0) {
    int best = 0;
    float bv = glog[0];
    if (glog[1] > bv) { bv = glog[1]; best = 1; }
    if (glog[2] > bv) { best = 2; }
    selbuf = best;
  }
  __syncthreads();
  const int e = selbuf;

  // ---- expert conv1 -> Bbuf (BN+ReLU) ----
  {
    float acc[4][4] = {};
    const int cob = wv * 16 + co4 * 4;
    conv4x4<128, 64>(g_we1T + e * 24576, Ebuf, lgrp, cob, acc);
    const float* bn1 = ebn1 + e * 256;
    const float* cb1 = e1b + e * 64;
#pragma unroll
    for (int k = 0; k < 4; ++k) {
      int co = cob + k;
      float inv = bn1[co] / sqrtf(bn1[192 + co] + BN_EPS);
      float add = bn1[64 + co] + (cb1[co] - bn1[128 + co]) * inv;
      if (lgrp < 15) {
#pragma unroll
        for (int l = 0; l < 4; ++l)
          Bbuf[co * 64 + (4 * lgrp + 1 + l)] =
              fmaxf(fmaf(acc[k][l], inv, add), 0.f);
      }
    }
  }
  // zero pad cols {0,61,62,63} of Bbuf's 64 rows (256 entries)
  {
    int r = tid >> 2;
    const int ctab[4] = {0, 61, 62, 63};
    Bbuf[r * 64 + ctab[tid & 3]] = 0.f;
  }
  __syncthreads();

  // ---- expert conv2: Bbuf -> C2 (overlays dead Ebuf rows 0..31) ----
  float* C2 = Ebuf;
  {
    float acc[2][4] = {};
    const int cob = wv * 8 + co4 * 2;  // 4 waves x 4 groups x 2 ch = 32
    conv2x4<64, 32>(g_we2T + e * 6144, Bbuf, lgrp, cob, acc);
    const float* bn2 = ebn2 + e * 128;
    const float* cb2 = e2b + e * 32;
#pragma unroll
    for (int k = 0; k < 2; ++k) {
      int co = cob + k;
      float inv = bn2[co] / sqrtf(bn2[96 + co] + BN_EPS);
      float add = bn2[32 + co] + (cb2[co] - bn2[64 + co]) * inv;
      if (lgrp < 15) {
#pragma unroll
        for (int l = 0; l < 4; ++l)
          C2[co * 64 + (4 * lgrp + 1 + l)] =
              fmaxf(fmaf(acc[k][l], inv, add), 0.f);
      }
    }
  }
  // zero pad cols {0,61,62,63} of C2's 32 rows (128 entries)
  if (tid < 128) {
    int r = tid >> 2;
    const int ctab[4] = {0, 61, 62, 63};
    C2[r * 64 + ctab[tid & 3]] = 0.f;
  }
  __syncthreads();

  // ---- expert conv3 + BN + ReLU + max over L -> mbuf[16] ----
  // lane = one position; stride-1 scalar reads (conflict-free).
  {
    float acc[4] = {};
    const int cob = wv * 4;
#pragma unroll 4
    for (int ci = 0; ci < 32; ++ci) {
      const float* row = C2 + ci * 64 + lane;
      float e0 = row[0], e1 = row[1], e2 = row[2];
      const float4* wp =
          reinterpret_cast<const float4*>(g_we3T + e * 1536 + (ci * 16 + cob) * 3);
      float4 w0 = wp[0], w1 = wp[1], w2 = wp[2];
      const float w[12] = {w0.x, w0.y, w0.z, w0.w, w1.x, w1.y,
                           w1.z, w1.w, w2.x, w2.y, w2.z, w2.w};
#pragma unroll
      for (int k = 0; k < 4; ++k)
        acc[k] = fmaf(e0, w[3 * k],
                      fmaf(e1, w[3 * k + 1], fmaf(e2, w[3 * k + 2], acc[k])));
    }
    const float* bn3 = ebn3 + e * 64;
    const float* cb3 = e3b + e * 16;
    const bool valid = (lane < 60);
#pragma unroll
    for (int k = 0; k < 4; ++k) {
      int co = cob + k;
      float inv = bn3[co] / sqrtf(bn3[48 + co] + BN_EPS);
      float add = bn3[16 + co] + (cb3[co] - bn3[32 + co]) * inv;
      float v = valid ? fmaxf(fmaf(acc[k], inv, add), 0.f) : -1e30f;
#pragma unroll
      for (int off = 1; off < 64; off <<= 1)
        v = fmaxf(v, __shfl_xor(v, off, 64));
      if (lane == 0) mbuf[co] = v;
    }
  }
  __syncthreads();

  // ---- head MLP 16->64->2 ----
  if (tid < 64) {
    float a = f1b[tid];
#pragma unroll
    for (int k = 0; k < 16; ++k) a = fmaf(mbuf[k], f1w[tid * 16 + k], a);
    o64[tid] = fmaxf(a, 0.f);
  }
  __syncthreads();
  if (tid < 2) {
    float a = f2b[tid];
#pragma unroll 8
    for (int k = 0; k < 64; ++k) a = fmaf(o64[k], f2w[tid * 64 + k], a);
    out[b * 2 + tid] = a;
  }
}

extern "C" void kernel_launch(void* const* d_in, const int* in_sizes, int n_in,
                              void* d_out, int out_size, void* d_ws,
                              size_t ws_size, hipStream_t stream) {
  const int* x = (const int*)d_in[0];
  const float* embt = (const float*)d_in[1];
  const float* gcw = (const float*)d_in[2];
  const float* gcb = (const float*)d_in[3];
  const float* gbn = (const float*)d_in[4];
  const float* gf1w = (const float*)d_in[5];
  const float* gf1b = (const float*)d_in[6];
  const float* gf2w = (const float*)d_in[7];
  const float* gf2b = (const float*)d_in[8];
  const float* e1w = (const float*)d_in[9];
  const float* e1b = (const float*)d_in[10];
  const float* ebn1 = (const float*)d_in[11];
  const float* e2w = (const float*)d_in[12];
  const float* e2b = (const float*)d_in[13];
  const float* ebn2 = (const float*)d_in[14];
  const float* e3w = (const float*)d_in[15];
  const float* e3b = (const float*)d_in[16];
  const float* ebn3 = (const float*)d_in[17];
  const float* f1w = (const float*)d_in[18];
  const float* f1b = (const float*)d_in[19];
  const float* f2w = (const float*)d_in[20];
  const float* f2b = (const float*)d_in[21];
  float* out = (float*)d_out;

  const int B = in_sizes[0] / 60;  // 16384

  transpose_w_kernel<<<(121344 + 255) / 256, 256, 0, stream>>>(gcw, e1w, e2w,
                                                               e3w);
  moe_fused_kernel<<<B, 256, 0, stream>>>(
      x, embt, gcb, gbn, gf1w, gf1b, gf2w, gf2b, e1b, ebn1, e2b, ebn2, e3b,
      ebn3, f1w, f1b, f2w, f2b, out);
}